// Round 5
// baseline (345.367 us; speedup 1.0000x reference)
//
#include <hip/hip_runtime.h>

#define N_NODES 100000
#define N_EDGES 1600000
#define NUM_GRAPHS 128

#define BSH 7
#define NBUCK 782                 // ceil(N_NODES / 128)
#define NBLKP 1000                // partition blocks (≈4/CU -> latency hiding)
#define EPB (N_EDGES / NBLKP)     // 1600
#define SOFF (NBUCK * NBLKP)      // src-region offset in cnt array
#define NSCAN (2 * NBUCK * NBLKP) // 1564000
#define SCAN_BS 1024
#define NBSC ((NSCAN + SCAN_BS - 1) / SCAN_BS)  // 1528

// ---------------- Phase A: per-block coarse histograms (dst & src) ----------------
__global__ __launch_bounds__(256) void part_hist(const int* __restrict__ src,
                                                 const int* __restrict__ dst,
                                                 int* __restrict__ cnt) {
    __shared__ int hd[NBUCK], hs[NBUCK];
    for (int i = threadIdx.x; i < NBUCK; i += 256) { hd[i] = 0; hs[i] = 0; }
    __syncthreads();
    int bk = blockIdx.x;
    int e0 = bk * EPB;
    for (int j = threadIdx.x; j < EPB; j += 256) {
        int e = e0 + j;
        atomicAdd(&hd[dst[e] >> BSH], 1);
        atomicAdd(&hs[src[e] >> BSH], 1);
    }
    __syncthreads();
    for (int i = threadIdx.x; i < NBUCK; i += 256) {
        cnt[i * NBLKP + bk] = hd[i];
        cnt[SOFF + i * NBLKP + bk] = hs[i];
    }
}

// ---------------- exclusive scan (in-place capable) ----------------
__global__ __launch_bounds__(256) void scan1(const int* __restrict__ cnt, int* __restrict__ excl,
                                             int* __restrict__ blksum, int n) {
    __shared__ int tmp[256];
    int t = threadIdx.x;
    int idx0 = blockIdx.x * SCAN_BS + t * 4;
    int v[4];
#pragma unroll
    for (int k = 0; k < 4; ++k) { int i = idx0 + k; v[k] = (i < n) ? cnt[i] : 0; }
    int sum = v[0] + v[1] + v[2] + v[3];
    tmp[t] = sum;
    __syncthreads();
    for (int off = 1; off < 256; off <<= 1) {
        int y = (t >= off) ? tmp[t - off] : 0;
        __syncthreads();
        tmp[t] += y;
        __syncthreads();
    }
    int run = (t > 0) ? tmp[t - 1] : 0;
#pragma unroll
    for (int k = 0; k < 4; ++k) { int i = idx0 + k; if (i < n) excl[i] = run; run += v[k]; }
    if (t == 255) blksum[blockIdx.x] = tmp[255];
}

// generalized: handles nb up to 256*C (serial C chunk per thread)
__global__ __launch_bounds__(256) void scan2(int* __restrict__ blksum, int nb) {
    __shared__ int tmp[256];
    int t = threadIdx.x;
    int C = (nb + 255) / 256;
    int base = t * C;
    int s = 0;
    for (int k = 0; k < C; ++k) { int i = base + k; if (i < nb) s += blksum[i]; }
    tmp[t] = s;
    __syncthreads();
    for (int off = 1; off < 256; off <<= 1) {
        int y = (t >= off) ? tmp[t - off] : 0;
        __syncthreads();
        tmp[t] += y;
        __syncthreads();
    }
    int run = (t > 0) ? tmp[t - 1] : 0;
    for (int k = 0; k < C; ++k) {
        int i = base + k;
        if (i < nb) { int v = blksum[i]; blksum[i] = run; run += v; }
    }
}

__global__ void scan3(int* __restrict__ excl, const int* __restrict__ blkoff, int n) {
    int i = blockIdx.x * 256 + threadIdx.x;
    if (i < n) excl[i] += blkoff[i >> 10];
}

// ---------------- Phase C: partition edges into coarse buckets (LDS cursors) ----------------
__global__ __launch_bounds__(256) void part_scatter(const int* __restrict__ src,
                                                    const int* __restrict__ dst,
                                                    const int* __restrict__ base,
                                                    unsigned* __restrict__ pdst,
                                                    unsigned char* __restrict__ psrc) {
    __shared__ int cd[NBUCK], cs[NBUCK];
    int bk = blockIdx.x;
    for (int i = threadIdx.x; i < NBUCK; i += 256) {
        cd[i] = base[i * NBLKP + bk];
        cs[i] = base[SOFF + i * NBLKP + bk] - N_EDGES;
    }
    __syncthreads();
    int e0 = bk * EPB;
    for (int j = threadIdx.x; j < EPB; j += 256) {
        int e = e0 + j;
        int s = src[e], d = dst[e];
        int pd = atomicAdd(&cd[d >> BSH], 1);
        pdst[pd] = (unsigned)s | ((unsigned)(d & 127) << 17);
        int ps = atomicAdd(&cs[s >> BSH], 1);
        psrc[ps] = (unsigned char)(s & 127);
    }
}

// ---------------- Phase D: fine CSR per bucket (128 nodes) ----------------
__global__ __launch_bounds__(256) void build_csr(const unsigned* __restrict__ pdst,
                                                 const int* __restrict__ base,
                                                 int* __restrict__ ecol, int* __restrict__ row_start,
                                                 float* __restrict__ isqi, int nN) {
    __shared__ int lh[128];
    __shared__ int lcur[128];
    int bu = blockIdx.x;
    int b0 = base[bu * NBLKP];
    int b1 = (bu == NBUCK - 1) ? N_EDGES : base[(bu + 1) * NBLKP];
    int t = threadIdx.x;
    if (t < 128) lh[t] = 0;
    __syncthreads();
    for (int j = b0 + t; j < b1; j += 256)
        atomicAdd(&lh[pdst[j] >> 17], 1);
    __syncthreads();
    int myc = (t < 128) ? lh[t] : 0;
    for (int off = 1; off < 128; off <<= 1) {
        int v = (t < 128 && t >= off) ? lh[t - off] : 0;
        __syncthreads();
        if (t < 128) lh[t] += v;
        __syncthreads();
    }
    if (t < 128) {
        int excl = lh[t] - myc;
        int node = (bu << BSH) + t;
        if (node < nN) {
            row_start[node] = b0 + excl;
            isqi[node] = rsqrtf(fmaxf((float)myc, 1.0f));
        }
        lcur[t] = b0 + excl;
    }
    __syncthreads();
    for (int j = b0 + t; j < b1; j += 256) {
        unsigned w = pdst[j];
        int off = w >> 17;
        int pos = atomicAdd(&lcur[off], 1);
        ecol[pos] = (int)(w & 0x1FFFFu);
    }
}

// ---------------- src degree -> isqo, fused x prescale into stride-72 padded xs ----------------
__global__ __launch_bounds__(256) void src_deg_prescale(const unsigned char* __restrict__ psrc,
                                                        const int* __restrict__ base,
                                                        const float* __restrict__ x,
                                                        float* __restrict__ isqo,
                                                        float* __restrict__ xs, int nN) {
    __shared__ int lh[128];
    __shared__ float sc[128];
    int bu = blockIdx.x;
    int b0 = base[SOFF + bu * NBLKP] - N_EDGES;
    int b1 = (bu == NBUCK - 1) ? N_EDGES : base[SOFF + (bu + 1) * NBLKP] - N_EDGES;
    int t = threadIdx.x;
    if (t < 128) lh[t] = 0;
    __syncthreads();
    for (int j = b0 + t; j < b1; j += 256)
        atomicAdd(&lh[psrc[j]], 1);
    __syncthreads();
    if (t < 128) {
        float v = rsqrtf(fmaxf((float)lh[t], 1.0f));
        sc[t] = v;
        int node = (bu << BSH) + t;
        if (node < nN) isqo[node] = v;
    }
    __syncthreads();
    int n0 = bu << BSH;
    int rows = min(128, nN - n0);
    for (int idx = t; idx < rows * 72; idx += 256) {
        int r = idx / 72, c = idx - r * 72;
        float val = (c < 69) ? x[(size_t)(n0 + r) * 69 + c] * sc[r] : 0.0f;
        xs[(size_t)(n0 + r) * 72 + c] = val;
    }
}

// ---------------- gather: agg[n] = dscale[n] * sum_{e in row n} feat[src_e] ----------------
// one wave per dst node; lanes 0..D/2-1 each hold a float2 of the row. Deep unroll for MLP.
template<int D>
__global__ void gather_kernel(const float* __restrict__ feat, const int* __restrict__ ecol,
                              const int* __restrict__ row_start, const float* __restrict__ dscale,
                              float* __restrict__ agg, int nN, int nE) {
    constexpr int L = D / 2;
    int wave = (int)(((unsigned)blockIdx.x * blockDim.x + threadIdx.x) >> 6);
    int lane = threadIdx.x & 63;
    if (wave >= nN) return;
    int beg = row_start[wave];
    int end = (wave == nN - 1) ? nE : row_start[wave + 1];
    float ax = 0.0f, ay = 0.0f;
    bool act = (lane < L);
    for (int j0 = beg; j0 < end; j0 += 64) {
        int ne = min(64, end - j0);
        int eidx = (lane < ne) ? ecol[j0 + lane] : 0;
        int k = 0;
        for (; k + 16 <= ne; k += 16) {
            float2 v[16];
#pragma unroll
            for (int u = 0; u < 16; ++u) {
                int s = __shfl(eidx, k + u);
                v[u] = act ? ((const float2*)(feat + (size_t)s * D))[lane] : make_float2(0.f, 0.f);
            }
#pragma unroll
            for (int u = 0; u < 16; ++u) { ax += v[u].x; ay += v[u].y; }
        }
        if (k + 8 <= ne) {
            float2 v[8];
#pragma unroll
            for (int u = 0; u < 8; ++u) {
                int s = __shfl(eidx, k + u);
                v[u] = act ? ((const float2*)(feat + (size_t)s * D))[lane] : make_float2(0.f, 0.f);
            }
#pragma unroll
            for (int u = 0; u < 8; ++u) { ax += v[u].x; ay += v[u].y; }
            k += 8;
        }
        if (k + 4 <= ne) {
            float2 v[4];
#pragma unroll
            for (int u = 0; u < 4; ++u) {
                int s = __shfl(eidx, k + u);
                v[u] = act ? ((const float2*)(feat + (size_t)s * D))[lane] : make_float2(0.f, 0.f);
            }
#pragma unroll
            for (int u = 0; u < 4; ++u) { ax += v[u].x; ay += v[u].y; }
            k += 4;
        }
        for (; k < ne; ++k) {
            int s = __shfl(eidx, k);
            float2 v = act ? ((const float2*)(feat + (size_t)s * D))[lane] : make_float2(0.f, 0.f);
            ax += v.x; ay += v.y;
        }
    }
    if (act) {
        float dsc = dscale[wave];
        ((float2*)(agg + (size_t)wave * D))[lane] = make_float2(ax * dsc, ay * dsc);
    }
}

// ---------------- register-blocked node GEMM ----------------
template<int KP, int K, int NO, bool RELU, bool SCALE>
__global__ __launch_bounds__(256) void node_gemm(const float* __restrict__ in,
                                                 const float* __restrict__ W,
                                                 const float* __restrict__ rowscale,
                                                 float* __restrict__ out, int nN) {
    constexpr int CG = NO / 8;
    constexpr int RT = 256 / CG;
    constexpr int ROWS = RT * 4;
    __shared__ float Wl[KP * NO];
    for (int i = threadIdx.x; i < KP * NO; i += 256)
        Wl[i] = (i < K * NO) ? W[i] : 0.0f;
    __syncthreads();

    int cg = threadIdx.x % CG;
    int rt = threadIdx.x / CG;
    int row0 = blockIdx.x * ROWS + rt * 4;
    int c0 = cg * 8;

    float4 accL[4] = {};
    float4 accH[4] = {};
    int rclamp[4];
#pragma unroll
    for (int r = 0; r < 4; ++r) rclamp[r] = min(row0 + r, nN - 1);

#pragma unroll 2
    for (int k4 = 0; k4 < KP / 4; ++k4) {
        float4 a[4];
#pragma unroll
        for (int r = 0; r < 4; ++r)
            a[r] = *(const float4*)(in + (size_t)rclamp[r] * KP + k4 * 4);
#pragma unroll
        for (int kk = 0; kk < 4; ++kk) {
            int k = k4 * 4 + kk;
            float4 wlo = *(const float4*)&Wl[k * NO + c0];
            float4 whi = *(const float4*)&Wl[k * NO + c0 + 4];
#pragma unroll
            for (int r = 0; r < 4; ++r) {
                float ar = (kk == 0) ? a[r].x : (kk == 1) ? a[r].y : (kk == 2) ? a[r].z : a[r].w;
                accL[r].x += ar * wlo.x; accL[r].y += ar * wlo.y;
                accL[r].z += ar * wlo.z; accL[r].w += ar * wlo.w;
                accH[r].x += ar * whi.x; accH[r].y += ar * whi.y;
                accH[r].z += ar * whi.z; accH[r].w += ar * whi.w;
            }
        }
    }

#pragma unroll
    for (int r = 0; r < 4; ++r) {
        int row = row0 + r;
        if (row < nN) {
            float4 lo = accL[r], hi = accH[r];
            if (SCALE) {
                float sc = rowscale[row];
                lo.x *= sc; lo.y *= sc; lo.z *= sc; lo.w *= sc;
                hi.x *= sc; hi.y *= sc; hi.z *= sc; hi.w *= sc;
            }
            if (RELU) {
                lo.x = fmaxf(lo.x, 0.f); lo.y = fmaxf(lo.y, 0.f);
                lo.z = fmaxf(lo.z, 0.f); lo.w = fmaxf(lo.w, 0.f);
                hi.x = fmaxf(hi.x, 0.f); hi.y = fmaxf(hi.y, 0.f);
                hi.z = fmaxf(hi.z, 0.f); hi.w = fmaxf(hi.w, 0.f);
            }
            *(float4*)(out + (size_t)row * NO + c0) = lo;
            *(float4*)(out + (size_t)row * NO + c0 + 4) = hi;
        }
    }
}

// ---------------- fused ReLU + per-graph max readout ----------------
__global__ void readout_kernel(const float* __restrict__ agg2, const int* __restrict__ gid,
                               unsigned* __restrict__ out, int nN) {
    const int NPW = 8;
    int wave = (int)(((unsigned)blockIdx.x * blockDim.x + threadIdx.x) >> 6);
    int lane = threadIdx.x & 63;
    int n0 = wave * NPW;
    if (n0 >= nN) return;
    int curg = gid[n0];
    float best = 0.0f;
    for (int i = 0; i < NPW; ++i) {
        int n = n0 + i;
        if (n >= nN) break;
        int g = gid[n];
        float v = fmaxf(agg2[(size_t)n * 64 + lane], 0.0f);
        if (g != curg) {
            atomicMax(&out[curg * 64 + lane], __float_as_uint(best));
            curg = g;
            best = v;
        } else {
            best = fmaxf(best, v);
        }
    }
    atomicMax(&out[curg * 64 + lane], __float_as_uint(best));
}

extern "C" void kernel_launch(void* const* d_in, const int* in_sizes, int n_in,
                              void* d_out, int out_size, void* d_ws, size_t ws_size,
                              hipStream_t stream) {
    const float* x   = (const float*)d_in[0];   // [100000, 69]
    const float* W1  = (const float*)d_in[1];   // [69, 128]
    const float* W2  = (const float*)d_in[2];   // [128, 64]
    const int*   src = (const int*)d_in[3];     // [1600000]
    const int*   dst = (const int*)d_in[4];     // [1600000]
    const int*   gid = (const int*)d_in[5];     // [100000] sorted

    char* w = (char*)d_ws;
    float* isqo    = (float*)w;                 w += N_NODES * 4;
    float* isqi    = (float*)w;                 w += N_NODES * 4;
    int* row_start = (int*)w;                   w += N_NODES * 4;
    int* ecol      = (int*)w;                   w += (size_t)N_EDGES * 4;
    int* cnt       = (int*)w;                   w += (size_t)NSCAN * 4;  // 6.26 MB
    int* blksum    = (int*)w;                   w += 2048 * 4;
    float* bufA    = (float*)w;                 w += (size_t)N_NODES * 72 * 4;  // agg1 -> y2s
    float* bufB    = (float*)w;                 // 51.2MB region, time-shared:
    unsigned* pdst      = (unsigned*)bufB;                                   // [nE] u32, dead after build_csr
    float* xs           = bufB;                                              // [N,72] f32, lives prescale..gather1
    unsigned char* psrc = (unsigned char*)bufB + (size_t)N_NODES * 72 * 4;   // [nE] u8, above xs, dead after src_deg_prescale
    // bufB proper (h1 [N,128] then agg2 [N,64]) starts life at gemm1

    hipMemsetAsync(d_out, 0, (size_t)out_size * sizeof(float), stream);

    // ----- two-level CSR build, no global atomics -----
    part_hist<<<NBLKP, 256, 0, stream>>>(src, dst, cnt);
    scan1<<<NBSC, 256, 0, stream>>>(cnt, cnt, blksum, NSCAN);
    scan2<<<1, 256, 0, stream>>>(blksum, NBSC);
    scan3<<<(NSCAN + 255) / 256, 256, 0, stream>>>(cnt, blksum, NSCAN);
    part_scatter<<<NBLKP, 256, 0, stream>>>(src, dst, cnt, pdst, psrc);
    build_csr<<<NBUCK, 256, 0, stream>>>(pdst, cnt, ecol, row_start, isqi, N_NODES);
    src_deg_prescale<<<NBUCK, 256, 0, stream>>>(psrc, cnt, x, isqo, xs, N_NODES);

    // ----- layer 1: gather(72) -> GEMM(+relu) -----
    gather_kernel<72><<<(N_NODES * 64 + 255) / 256, 256, 0, stream>>>(
        xs, ecol, row_start, isqi, bufA, N_NODES, N_EDGES);
    node_gemm<72, 69, 128, true, false><<<(N_NODES + 63) / 64, 256, 0, stream>>>(
        bufA, W1, nullptr, bufB, N_NODES);

    // ----- layer 2: GEMM(*isqo) -> gather(64) -----
    node_gemm<128, 128, 64, false, true><<<(N_NODES + 127) / 128, 256, 0, stream>>>(
        bufB, W2, isqo, bufA, N_NODES);
    gather_kernel<64><<<(N_NODES * 64 + 255) / 256, 256, 0, stream>>>(
        bufA, ecol, row_start, isqi, bufB, N_NODES, N_EDGES);

    // ----- fused ReLU + per-graph max readout -----
    readout_kernel<<<((N_NODES + 7) / 8 * 64 + 255) / 256, 256, 0, stream>>>(
        bufB, gid, (unsigned*)d_out, N_NODES);
}

// Round 6
// 296.703 us; speedup vs baseline: 1.1640x; 1.1640x over previous
//
#include <hip/hip_runtime.h>

#define N_NODES 100000
#define N_EDGES 1600000
#define NUM_GRAPHS 128

#define BSH 7
#define NBUCK 782                 // ceil(N_NODES / 128)
#define NBLKP 512                 // partition blocks (2/CU)
#define EPB (N_EDGES / NBLKP)     // 3125
#define SOFF (NBUCK * NBLKP)      // src-region offset in cnt array
#define NSCAN (2 * NBUCK * NBLKP) // 800768
#define SCAN_BS 1024
#define NBSC ((NSCAN + SCAN_BS - 1) / SCAN_BS)  // 782

__device__ __forceinline__ unsigned bf16pair(float a, float b) {
    unsigned ua = __float_as_uint(a), ub = __float_as_uint(b);
    ua = (ua + 0x7FFFu + ((ua >> 16) & 1u)) >> 16;
    ub = (ub + 0x7FFFu + ((ub >> 16) & 1u)) >> 16;
    return ua | (ub << 16);
}
__device__ __forceinline__ float bflo(unsigned u) { return __uint_as_float(u << 16); }
__device__ __forceinline__ float bfhi(unsigned u) { return __uint_as_float(u & 0xFFFF0000u); }

// ---------------- Phase A: per-block coarse histograms (dst & src) ----------------
__global__ __launch_bounds__(256) void part_hist(const int* __restrict__ src,
                                                 const int* __restrict__ dst,
                                                 int* __restrict__ cnt) {
    __shared__ int hd[NBUCK], hs[NBUCK];
    for (int i = threadIdx.x; i < NBUCK; i += 256) { hd[i] = 0; hs[i] = 0; }
    __syncthreads();
    int bk = blockIdx.x;
    int e0 = bk * EPB;
    for (int j = threadIdx.x; j < EPB; j += 256) {
        int e = e0 + j;
        atomicAdd(&hd[dst[e] >> BSH], 1);
        atomicAdd(&hs[src[e] >> BSH], 1);
    }
    __syncthreads();
    for (int i = threadIdx.x; i < NBUCK; i += 256) {
        cnt[i * NBLKP + bk] = hd[i];
        cnt[SOFF + i * NBLKP + bk] = hs[i];
    }
}

// ---------------- exclusive scan (in-place capable) ----------------
__global__ __launch_bounds__(256) void scan1(const int* __restrict__ cnt, int* __restrict__ excl,
                                             int* __restrict__ blksum, int n) {
    __shared__ int tmp[256];
    int t = threadIdx.x;
    int idx0 = blockIdx.x * SCAN_BS + t * 4;
    int v[4];
#pragma unroll
    for (int k = 0; k < 4; ++k) { int i = idx0 + k; v[k] = (i < n) ? cnt[i] : 0; }
    int sum = v[0] + v[1] + v[2] + v[3];
    tmp[t] = sum;
    __syncthreads();
    for (int off = 1; off < 256; off <<= 1) {
        int y = (t >= off) ? tmp[t - off] : 0;
        __syncthreads();
        tmp[t] += y;
        __syncthreads();
    }
    int run = (t > 0) ? tmp[t - 1] : 0;
#pragma unroll
    for (int k = 0; k < 4; ++k) { int i = idx0 + k; if (i < n) excl[i] = run; run += v[k]; }
    if (t == 255) blksum[blockIdx.x] = tmp[255];
}

// generalized: handles nb up to 256*C (serial C chunk per thread)
__global__ __launch_bounds__(256) void scan2(int* __restrict__ blksum, int nb) {
    __shared__ int tmp[256];
    int t = threadIdx.x;
    int C = (nb + 255) / 256;
    int base = t * C;
    int s = 0;
    for (int k = 0; k < C; ++k) { int i = base + k; if (i < nb) s += blksum[i]; }
    tmp[t] = s;
    __syncthreads();
    for (int off = 1; off < 256; off <<= 1) {
        int y = (t >= off) ? tmp[t - off] : 0;
        __syncthreads();
        tmp[t] += y;
        __syncthreads();
    }
    int run = (t > 0) ? tmp[t - 1] : 0;
    for (int k = 0; k < C; ++k) {
        int i = base + k;
        if (i < nb) { int v = blksum[i]; blksum[i] = run; run += v; }
    }
}

__global__ void scan3(int* __restrict__ excl, const int* __restrict__ blkoff, int n) {
    int i = blockIdx.x * 256 + threadIdx.x;
    if (i < n) excl[i] += blkoff[i >> 10];
}

// ---------------- Phase C: partition edges into coarse buckets (LDS cursors) ----------------
__global__ __launch_bounds__(256) void part_scatter(const int* __restrict__ src,
                                                    const int* __restrict__ dst,
                                                    const int* __restrict__ base,
                                                    unsigned* __restrict__ pdst,
                                                    unsigned char* __restrict__ psrc) {
    __shared__ int cd[NBUCK], cs[NBUCK];
    int bk = blockIdx.x;
    for (int i = threadIdx.x; i < NBUCK; i += 256) {
        cd[i] = base[i * NBLKP + bk];
        cs[i] = base[SOFF + i * NBLKP + bk] - N_EDGES;
    }
    __syncthreads();
    int e0 = bk * EPB;
    for (int j = threadIdx.x; j < EPB; j += 256) {
        int e = e0 + j;
        int s = src[e], d = dst[e];
        int pd = atomicAdd(&cd[d >> BSH], 1);
        pdst[pd] = (unsigned)s | ((unsigned)(d & 127) << 17);
        int ps = atomicAdd(&cs[s >> BSH], 1);
        psrc[ps] = (unsigned char)(s & 127);
    }
}

// ---------------- Phase D: fine CSR per bucket (128 nodes) ----------------
__global__ __launch_bounds__(256) void build_csr(const unsigned* __restrict__ pdst,
                                                 const int* __restrict__ base,
                                                 int* __restrict__ ecol, int* __restrict__ row_start,
                                                 float* __restrict__ isqi, int nN) {
    __shared__ int lh[128];
    __shared__ int lcur[128];
    int bu = blockIdx.x;
    int b0 = base[bu * NBLKP];
    int b1 = (bu == NBUCK - 1) ? N_EDGES : base[(bu + 1) * NBLKP];
    int t = threadIdx.x;
    if (t < 128) lh[t] = 0;
    __syncthreads();
    for (int j = b0 + t; j < b1; j += 256)
        atomicAdd(&lh[pdst[j] >> 17], 1);
    __syncthreads();
    int myc = (t < 128) ? lh[t] : 0;
    for (int off = 1; off < 128; off <<= 1) {
        int v = (t < 128 && t >= off) ? lh[t - off] : 0;
        __syncthreads();
        if (t < 128) lh[t] += v;
        __syncthreads();
    }
    if (t < 128) {
        int excl = lh[t] - myc;
        int node = (bu << BSH) + t;
        if (node < nN) {
            row_start[node] = b0 + excl;
            isqi[node] = rsqrtf(fmaxf((float)myc, 1.0f));
        }
        lcur[t] = b0 + excl;
    }
    __syncthreads();
    for (int j = b0 + t; j < b1; j += 256) {
        unsigned w = pdst[j];
        int off = w >> 17;
        int pos = atomicAdd(&lcur[off], 1);
        ecol[pos] = (int)(w & 0x1FFFFu);
    }
}

// ---------------- src degree -> isqo, fused prescale: xs = bf16(x * isqo), 36 u32/row ----------------
__global__ __launch_bounds__(256) void src_deg_prescale(const unsigned char* __restrict__ psrc,
                                                        const int* __restrict__ base,
                                                        const float* __restrict__ x,
                                                        float* __restrict__ isqo,
                                                        unsigned* __restrict__ xsu, int nN) {
    __shared__ int lh[128];
    __shared__ float sc[128];
    int bu = blockIdx.x;
    int b0 = base[SOFF + bu * NBLKP] - N_EDGES;
    int b1 = (bu == NBUCK - 1) ? N_EDGES : base[SOFF + (bu + 1) * NBLKP] - N_EDGES;
    int t = threadIdx.x;
    if (t < 128) lh[t] = 0;
    __syncthreads();
    for (int j = b0 + t; j < b1; j += 256)
        atomicAdd(&lh[psrc[j]], 1);
    __syncthreads();
    if (t < 128) {
        float v = rsqrtf(fmaxf((float)lh[t], 1.0f));
        sc[t] = v;
        int node = (bu << BSH) + t;
        if (node < nN) isqo[node] = v;
    }
    __syncthreads();
    int n0 = bu << BSH;
    int rows = min(128, nN - n0);
    for (int idx = t; idx < rows * 36; idx += 256) {
        int r = idx / 36, c2 = idx - r * 36;
        float s = sc[r];
        int c = 2 * c2;
        float a = (c < 69) ? x[(size_t)(n0 + r) * 69 + c] * s : 0.0f;
        float b = (c + 1 < 69) ? x[(size_t)(n0 + r) * 69 + c + 1] * s : 0.0f;
        xsu[(size_t)(n0 + r) * 36 + c2] = bf16pair(a, b);
    }
}

// ---------------- gather1: agg[n][0..71] (f32) = dscale[n] * sum feat_bf16[src] ----------------
// one wave per dst node; lanes 0..35 hold one u32 (2 bf16) of the row
__global__ void gather1_kernel(const unsigned* __restrict__ feat, const int* __restrict__ ecol,
                               const int* __restrict__ row_start, const float* __restrict__ dscale,
                               float* __restrict__ agg, int nN, int nE) {
    int wave = (int)(((unsigned)blockIdx.x * blockDim.x + threadIdx.x) >> 6);
    int lane = threadIdx.x & 63;
    if (wave >= nN) return;
    int beg = row_start[wave];
    int end = (wave == nN - 1) ? nE : row_start[wave + 1];
    bool act = (lane < 36);
    float ax = 0.0f, ay = 0.0f;
    for (int j0 = beg; j0 < end; j0 += 64) {
        int ne = min(64, end - j0);
        int eidx = (lane < ne) ? ecol[j0 + lane] : 0;
        int k = 0;
        for (; k + 8 <= ne; k += 8) {
            unsigned v[8];
#pragma unroll
            for (int u = 0; u < 8; ++u) {
                int s = __shfl(eidx, k + u);
                v[u] = act ? feat[(size_t)s * 36 + lane] : 0u;
            }
#pragma unroll
            for (int u = 0; u < 8; ++u) { ax += bflo(v[u]); ay += bfhi(v[u]); }
        }
        for (; k + 2 <= ne; k += 2) {
            int s0 = __shfl(eidx, k), s1 = __shfl(eidx, k + 1);
            unsigned v0 = act ? feat[(size_t)s0 * 36 + lane] : 0u;
            unsigned v1 = act ? feat[(size_t)s1 * 36 + lane] : 0u;
            ax += bflo(v0) + bflo(v1); ay += bfhi(v0) + bfhi(v1);
        }
        for (; k < ne; ++k) {
            int s = __shfl(eidx, k);
            unsigned v = act ? feat[(size_t)s * 36 + lane] : 0u;
            ax += bflo(v); ay += bfhi(v);
        }
    }
    if (act) {
        float dsc = dscale[wave];
        ((float2*)(agg + (size_t)wave * 72))[lane] = make_float2(ax * dsc, ay * dsc);
    }
}

// ---------------- gather2: agg[n][0..63] (f32) = dscale[n] * sum feat_bf16[src]; 2 edges/step ----------------
// lanes 0..31 = edge e chunks, lanes 32..63 = edge e+1 chunks; final shfl_xor(32) combine
__global__ void gather2_kernel(const unsigned* __restrict__ feat, const int* __restrict__ ecol,
                               const int* __restrict__ row_start, const float* __restrict__ dscale,
                               float* __restrict__ agg, int nN, int nE) {
    int wave = (int)(((unsigned)blockIdx.x * blockDim.x + threadIdx.x) >> 6);
    int lane = threadIdx.x & 63;
    if (wave >= nN) return;
    int beg = row_start[wave];
    int end = (wave == nN - 1) ? nE : row_start[wave + 1];
    int half = lane >> 5;
    int c = lane & 31;
    float ax = 0.0f, ay = 0.0f;
    for (int j0 = beg; j0 < end; j0 += 64) {
        int ne = min(64, end - j0);
        int eidx = (lane < ne) ? ecol[j0 + lane] : 0;
        int k = 0;
        for (; k + 16 <= ne; k += 16) {
            unsigned v[8];
#pragma unroll
            for (int u = 0; u < 8; ++u) {
                int s = __shfl(eidx, k + 2 * u + half);
                v[u] = feat[(size_t)s * 32 + c];
            }
#pragma unroll
            for (int u = 0; u < 8; ++u) { ax += bflo(v[u]); ay += bfhi(v[u]); }
        }
        for (; k + 2 <= ne; k += 2) {
            int s = __shfl(eidx, k + half);
            unsigned v = feat[(size_t)s * 32 + c];
            ax += bflo(v); ay += bfhi(v);
        }
        if (k < ne) {
            int s = __shfl(eidx, k);
            if (half == 0) {
                unsigned v = feat[(size_t)s * 32 + c];
                ax += bflo(v); ay += bfhi(v);
            }
        }
    }
    ax += __shfl_xor(ax, 32);
    ay += __shfl_xor(ay, 32);
    if (half == 0) {
        float dsc = dscale[wave];
        ((float2*)(agg + (size_t)wave * 64))[c] = make_float2(ax * dsc, ay * dsc);
    }
}

// ---------------- register-blocked node GEMM (f32 A/W; optional bf16-packed output) ----------------
template<int KP, int K, int NO, bool RELU, bool SCALE, bool BF16OUT>
__global__ __launch_bounds__(256) void node_gemm(const float* __restrict__ in,
                                                 const float* __restrict__ W,
                                                 const float* __restrict__ rowscale,
                                                 void* __restrict__ out, int nN) {
    constexpr int CG = NO / 8;
    constexpr int RT = 256 / CG;
    constexpr int ROWS = RT * 4;
    __shared__ float Wl[KP * NO];
    for (int i = threadIdx.x; i < KP * NO; i += 256)
        Wl[i] = (i < K * NO) ? W[i] : 0.0f;
    __syncthreads();

    int cg = threadIdx.x % CG;
    int rt = threadIdx.x / CG;
    int row0 = blockIdx.x * ROWS + rt * 4;
    int c0 = cg * 8;

    float4 accL[4] = {};
    float4 accH[4] = {};
    int rclamp[4];
#pragma unroll
    for (int r = 0; r < 4; ++r) rclamp[r] = min(row0 + r, nN - 1);

#pragma unroll 2
    for (int k4 = 0; k4 < KP / 4; ++k4) {
        float4 a[4];
#pragma unroll
        for (int r = 0; r < 4; ++r)
            a[r] = *(const float4*)(in + (size_t)rclamp[r] * KP + k4 * 4);
#pragma unroll
        for (int kk = 0; kk < 4; ++kk) {
            int k = k4 * 4 + kk;
            float4 wlo = *(const float4*)&Wl[k * NO + c0];
            float4 whi = *(const float4*)&Wl[k * NO + c0 + 4];
#pragma unroll
            for (int r = 0; r < 4; ++r) {
                float ar = (kk == 0) ? a[r].x : (kk == 1) ? a[r].y : (kk == 2) ? a[r].z : a[r].w;
                accL[r].x += ar * wlo.x; accL[r].y += ar * wlo.y;
                accL[r].z += ar * wlo.z; accL[r].w += ar * wlo.w;
                accH[r].x += ar * whi.x; accH[r].y += ar * whi.y;
                accH[r].z += ar * whi.z; accH[r].w += ar * whi.w;
            }
        }
    }

#pragma unroll
    for (int r = 0; r < 4; ++r) {
        int row = row0 + r;
        if (row < nN) {
            float4 lo = accL[r], hi = accH[r];
            if (SCALE) {
                float sc = rowscale[row];
                lo.x *= sc; lo.y *= sc; lo.z *= sc; lo.w *= sc;
                hi.x *= sc; hi.y *= sc; hi.z *= sc; hi.w *= sc;
            }
            if (RELU) {
                lo.x = fmaxf(lo.x, 0.f); lo.y = fmaxf(lo.y, 0.f);
                lo.z = fmaxf(lo.z, 0.f); lo.w = fmaxf(lo.w, 0.f);
                hi.x = fmaxf(hi.x, 0.f); hi.y = fmaxf(hi.y, 0.f);
                hi.z = fmaxf(hi.z, 0.f); hi.w = fmaxf(hi.w, 0.f);
            }
            if (BF16OUT) {
                unsigned* ob = (unsigned*)out;
                uint4 p;
                p.x = bf16pair(lo.x, lo.y); p.y = bf16pair(lo.z, lo.w);
                p.z = bf16pair(hi.x, hi.y); p.w = bf16pair(hi.z, hi.w);
                *(uint4*)(ob + (size_t)row * (NO / 2) + c0 / 2) = p;
            } else {
                float* of = (float*)out;
                *(float4*)(of + (size_t)row * NO + c0) = lo;
                *(float4*)(of + (size_t)row * NO + c0 + 4) = hi;
            }
        }
    }
}

// ---------------- fused ReLU + per-graph max readout ----------------
__global__ void readout_kernel(const float* __restrict__ agg2, const int* __restrict__ gid,
                               unsigned* __restrict__ out, int nN) {
    const int NPW = 8;
    int wave = (int)(((unsigned)blockIdx.x * blockDim.x + threadIdx.x) >> 6);
    int lane = threadIdx.x & 63;
    int n0 = wave * NPW;
    if (n0 >= nN) return;
    int curg = gid[n0];
    float best = 0.0f;
    for (int i = 0; i < NPW; ++i) {
        int n = n0 + i;
        if (n >= nN) break;
        int g = gid[n];
        float v = fmaxf(agg2[(size_t)n * 64 + lane], 0.0f);
        if (g != curg) {
            atomicMax(&out[curg * 64 + lane], __float_as_uint(best));
            curg = g;
            best = v;
        } else {
            best = fmaxf(best, v);
        }
    }
    atomicMax(&out[curg * 64 + lane], __float_as_uint(best));
}

extern "C" void kernel_launch(void* const* d_in, const int* in_sizes, int n_in,
                              void* d_out, int out_size, void* d_ws, size_t ws_size,
                              hipStream_t stream) {
    const float* x   = (const float*)d_in[0];   // [100000, 69]
    const float* W1  = (const float*)d_in[1];   // [69, 128]
    const float* W2  = (const float*)d_in[2];   // [128, 64]
    const int*   src = (const int*)d_in[3];     // [1600000]
    const int*   dst = (const int*)d_in[4];     // [1600000]
    const int*   gid = (const int*)d_in[5];     // [100000] sorted

    char* w = (char*)d_ws;
    float* isqo    = (float*)w;                 w += N_NODES * 4;
    float* isqi    = (float*)w;                 w += N_NODES * 4;
    int* row_start = (int*)w;                   w += N_NODES * 4;
    int* ecol      = (int*)w;                   w += (size_t)N_EDGES * 4;
    int* cnt       = (int*)w;                   w += (size_t)NSCAN * 4;   // 3.2 MB
    int* blksum    = (int*)w;                   w += 2048 * 4;
    float* bufA    = (float*)w;                 w += (size_t)N_NODES * 72 * 4;  // agg1 f32 [N,72] -> y2s bf16 [N,64]
    char* bufB     = w;                         // time-shared region:
    unsigned* pdst      = (unsigned*)bufB;                                  // [nE] u32, dead after build_csr
    unsigned* xsu       = (unsigned*)bufB;                                  // [N,36] u32 (bf16 x*isqo), prescale..gather1
    unsigned char* psrc = (unsigned char*)bufB + (size_t)N_NODES * 36 * 4;  // [nE] u8, dead after src_deg_prescale
    float* h1           = (float*)bufB;                                     // [N,128] f32, gemm1..gemm2
    float* agg2         = (float*)bufB;                                     // [N,64] f32, gather2..readout

    hipMemsetAsync(d_out, 0, (size_t)out_size * sizeof(float), stream);

    // ----- two-level CSR build, no global atomics -----
    part_hist<<<NBLKP, 256, 0, stream>>>(src, dst, cnt);
    scan1<<<NBSC, 256, 0, stream>>>(cnt, cnt, blksum, NSCAN);
    scan2<<<1, 256, 0, stream>>>(blksum, NBSC);
    scan3<<<(NSCAN + 255) / 256, 256, 0, stream>>>(cnt, blksum, NSCAN);
    part_scatter<<<NBLKP, 256, 0, stream>>>(src, dst, cnt, pdst, psrc);
    build_csr<<<NBUCK, 256, 0, stream>>>(pdst, cnt, ecol, row_start, isqi, N_NODES);
    src_deg_prescale<<<NBUCK, 256, 0, stream>>>(psrc, cnt, x, isqo, xsu, N_NODES);

    // ----- layer 1: gather(bf16 72) -> GEMM(+relu) -----
    gather1_kernel<<<(N_NODES * 64 + 255) / 256, 256, 0, stream>>>(
        xsu, ecol, row_start, isqi, bufA, N_NODES, N_EDGES);
    node_gemm<72, 69, 128, true, false, false><<<(N_NODES + 63) / 64, 256, 0, stream>>>(
        bufA, W1, nullptr, h1, N_NODES);

    // ----- layer 2: GEMM(*isqo -> bf16) -> gather(bf16 64) -----
    node_gemm<128, 128, 64, false, true, true><<<(N_NODES + 127) / 128, 256, 0, stream>>>(
        h1, W2, isqo, (void*)bufA, N_NODES);
    gather2_kernel<<<(N_NODES * 64 + 255) / 256, 256, 0, stream>>>(
        (const unsigned*)bufA, ecol, row_start, isqi, agg2, N_NODES, N_EDGES);

    // ----- fused ReLU + per-graph max readout -----
    readout_kernel<<<((N_NODES + 7) / 8 * 64 + 255) / 256, 256, 0, stream>>>(
        agg2, gid, (unsigned*)d_out, N_NODES);
}